// Round 13
// baseline (113.381 us; speedup 1.0000x reference)
//
#include <hip/hip_runtime.h>
#include <hip/hip_fp16.h>
#include <math.h>

#define N 8192
#define H 64
#define B 8
#define MAXDEG 128
#define REPS 8

// ---- workspace layout (bytes) ----
// zeroed each call by k_zero:
#define OFF_CNT  0ULL            // 8192 u32 = 32768
#define OFF_WR   32768ULL        // REPS*8*64 f32 = 16384
#define OFF_PR   49152ULL        // 16384
#define OFF_NLR  65536ULL        // REPS*8 f32 = 256
#define ZERO_END 65792ULL        // /16 = 4112 float4
// not zeroed:
#define OFF_COLS 65792ULL        // 8192*128 u16 = 2,097,152
#define OFF_TGT  2162944ULL      // 512 f32 = 2048
#define OFF_UV   2164992ULL      // 3*64 f32 = 768
#define OFF_REC  2165760ULL      // 8192*64 u32 = 2,097,152 (256B rows)
// end ~4.3 MB

// K0: zero cnt + replica accumulators (~64 KB)
__global__ __launch_bounds__(256) void k_zero(float4* __restrict__ p) {
    unsigned i = blockIdx.x * 256u + threadIdx.x;
    if (i < (unsigned)(ZERO_END / 16))
        p[i] = make_float4(0.f, 0.f, 0.f, 0.f);
}

// K1: append edges (1 edge/thread; dedup in K2)
__global__ __launch_bounds__(256) void k_edges(const int* __restrict__ ei, int nE,
                                               unsigned* __restrict__ cnt,
                                               unsigned short* __restrict__ cols) {
    int e = blockIdx.x * 256 + threadIdx.x;
    if (e >= nE) return;
    int r = ei[e];
    int c = ei[nE + e];
    unsigned k = atomicAdd(&cnt[r], 1u);
    if (k < MAXDEG) cols[r * MAXDEG + k] = (unsigned short)c;
}

// K2: per-wave {dedup -> dis -> packed record} for 2 rows; uvec on blk0/wv0.
// rec[m][lane] u32 = f16(dis_m * (W_g@ne[m])_lane) << 16 | f16(aux_lane)
// aux: lane<8: dis*x0_b; 8..15: dis*x1_b; 16: dis; 17..24: pmask_b; else 0.
__global__ __launch_bounds__(256) void k_prep(const float* __restrict__ ne,
                                              const float* __restrict__ W_g,
                                              const float* __restrict__ W_sp,
                                              const float* __restrict__ b_sp,
                                              const float* __restrict__ x,
                                              const float* __restrict__ pmask,
                                              unsigned* __restrict__ cnt,
                                              unsigned short* __restrict__ cols,
                                              unsigned* __restrict__ rec,
                                              float* __restrict__ uvec) {
    __shared__ float wgs[H * 65];                // padded W_g
    __shared__ unsigned short ls[4][MAXDEG];     // dedup staging
    const int tid = threadIdx.x, lane = tid & 63, wv = tid >> 6;
    const int bid = blockIdx.x;

    for (int e = tid; e < H * H; e += 256)
        wgs[(e >> 6) * 65 + (e & 63)] = W_g[e];
    __syncthreads();

    float wr[H];
#pragma unroll
    for (int k = 0; k < H; ++k) wr[k] = wgs[lane * 65 + k];

    if (bid == 0 && wv == 0) {   // uvec = {W_g@Wsp0, W_g@Wsp1, W_g@b_sp}
        float v0 = W_sp[lane * 2 + 0], v1 = W_sp[lane * 2 + 1], vb = b_sp[lane];
        float a0 = 0.f, a1 = 0.f, a2 = 0.f;
#pragma unroll
        for (int k = 0; k < H; ++k) {
            a0 = fmaf(wr[k], __shfl(v0, k, 64), a0);
            a1 = fmaf(wr[k], __shfl(v1, k, 64), a1);
            a2 = fmaf(wr[k], __shfl(vb, k, 64), a2);
        }
        uvec[lane] = a0; uvec[64 + lane] = a1; uvec[128 + lane] = a2;
    }

    for (int i = 0; i < 2; ++i) {
        const int r = (bid * 4 + wv) * 2 + i;
        // --- dedup row r ---
        const int kraw = min((int)cnt[r], MAXDEG);
        unsigned short* cl = &cols[r * MAXDEG];
        for (int t = lane; t < kraw; t += 64) ls[wv][t] = cl[t];
        int c0 = (lane < kraw) ? (int)ls[wv][lane] : -1;
        int dup0 = 0;
        for (int j = 0; j < lane && j < kraw; ++j)
            dup0 |= ((int)ls[wv][j] == c0);
        unsigned long long m0 = __ballot((lane < kraw) && !dup0);
        unsigned long long below = (1ULL << lane) - 1ULL;
        unsigned tot = __popcll(m0);
        if ((lane < kraw) && !dup0)
            cl[__popcll(m0 & below)] = (unsigned short)c0;
        if (kraw > 64) {                          // wave-uniform, rare
            const int i1 = lane + 64;
            int c1 = (i1 < kraw) ? (int)ls[wv][i1] : -2;
            int dup1 = 0;
            for (int j = 0; j < i1 && j < kraw; ++j)
                dup1 |= ((int)ls[wv][j] == c1);
            unsigned long long m1 = __ballot((i1 < kraw) && !dup1);
            if ((i1 < kraw) && !dup1)
                cl[tot + __popcll(m1 & below)] = (unsigned short)c1;
            tot += __popcll(m1);
        }
        if (lane == 0) cnt[r] = tot;
        const float dis = rsqrtf((float)(tot + 1u));

        // --- aux for row r ---
        float xvx = 0.f, xvy = 0.f, pm = 0.f;
        if (lane < 8) {
            float2 t2 = ((const float2*)x)[lane * N + r];
            xvx = t2.x; xvy = t2.y;
        }
        if (lane >= 17 && lane < 25) pm = pmask[(lane - 17) * N + r];
        float yv = __shfl(xvy, lane & 7, 64);
        float aux = (lane < 8)   ? dis * xvx
                  : (lane < 16)  ? dis * yv
                  : (lane == 16) ? dis
                  : (lane < 25)  ? pm : 0.f;

        // --- P part: dis * (W_g @ ne[r])_lane ---
        const float4* ne4 = (const float4*)(ne + (size_t)r * H);
        float acc = 0.f;
#pragma unroll
        for (int kk = 0; kk < 16; ++kk) {
            float4 h4 = ne4[kk];
            acc = fmaf(wr[4 * kk + 0], h4.x, acc);
            acc = fmaf(wr[4 * kk + 1], h4.y, acc);
            acc = fmaf(wr[4 * kk + 2], h4.z, acc);
            acc = fmaf(wr[4 * kk + 3], h4.w, acc);
        }
        unsigned w = ((unsigned)__half_as_ushort(__float2half(dis * acc)) << 16)
                   |  (unsigned)__half_as_ushort(__float2half(aux));
        rec[(size_t)r * 64 + lane] = w;
    }
}

__device__ __forceinline__ void acc_u32(unsigned u, float& p, float& a) {
    float2 f = __half22float2(*(const __half2*)&u);   // .y = P (hi), .x = aux (lo)
    p += f.y; a += f.x;
}

// K3: gather phase — 4 rows per wave, INTERLEAVED: inner iteration issues 4
// independent 256B row loads (structural MLP=4) and each wave streams ~132
// loads (long stream = sustained pipeline; R1 evidence: 27 gathers/ns at
// 264-load streams vs 5/ns at 10-load streams). Col indices are wave-uniform
// -> scalar loads on the SMEM pipe. 512 blocks x 256 thr; 16 rows/block;
// LDS block reduction -> 1 global atomic per element per block.
__global__ __launch_bounds__(256, 8) void k_spmm(const unsigned* __restrict__ rec,
                                                 const unsigned* __restrict__ cnt,
                                                 const unsigned short* __restrict__ cols,
                                                 const float* __restrict__ uvec,
                                                 const float* __restrict__ b_g,
                                                 const int* __restrict__ target,
                                                 float* __restrict__ wr_,
                                                 float* __restrict__ pr_,
                                                 float* __restrict__ nlr,
                                                 float* __restrict__ tgt) {
    __shared__ float lw[B * H];
    __shared__ float lp[B * H];
    __shared__ float lnl[B];
    const int tid = threadIdx.x;
    const int lane = tid & 63, wv = tid >> 6;
    const int wid = blockIdx.x * 4 + wv;          // [0, 2048)

    lw[tid] = 0.f; lw[tid + 256] = 0.f;
    lp[tid] = 0.f; lp[tid + 256] = 0.f;
    if (tid < B) lnl[tid] = 0.f;
    __syncthreads();

    const float u0 = uvec[lane], u1 = uvec[64 + lane], ub = uvec[128 + lane];
    const float bg = b_g[lane];
    int tg[B];
#pragma unroll
    for (int b = 0; b < B; ++b) tg[b] = target[b];

    // ---- 4 rows, interleaved gather streams ----
    int   r_[4], kc_[4];
    float sp_[4], sx_[4], fx_[4];
    const unsigned short* cl_[4];
#pragma unroll
    for (int i = 0; i < 4; ++i) {
        const int r = wid * 4 + i;
        r_[i] = r;
        kc_[i] = min((int)cnt[r], MAXDEG);
        cl_[i] = &cols[r * MAXDEG];
        unsigned v = rec[(size_t)r * 64 + lane];
        float2 f = __half22float2(*(const __half2*)&v);
        sp_[i] = f.y;                              // eye term
        sx_[i] = f.x;
        fx_[i] = f.x;                              // own aux kept for epilogue
    }
    const int kmax = max(max(kc_[0], kc_[1]), max(kc_[2], kc_[3]));
    for (int k = 0; k < kmax; ++k) {
        // issue 4 independent loads (select-to-zero: f16 0x0 decodes to 0.0)
        unsigned v0 = 0u, v1 = 0u, v2 = 0u, v3 = 0u;
        if (k < kc_[0]) v0 = rec[(size_t)cl_[0][k] * 64 + lane];
        if (k < kc_[1]) v1 = rec[(size_t)cl_[1][k] * 64 + lane];
        if (k < kc_[2]) v2 = rec[(size_t)cl_[2][k] * 64 + lane];
        if (k < kc_[3]) v3 = rec[(size_t)cl_[3][k] * 64 + lane];
        acc_u32(v0, sp_[0], sx_[0]);
        acc_u32(v1, sp_[1], sx_[1]);
        acc_u32(v2, sp_[2], sx_[2]);
        acc_u32(v3, sp_[3], sx_[3]);
    }

    // ---- epilogue per row: reconstruct z per batch, accumulate into LDS ----
#pragma unroll
    for (int i = 0; i < 4; ++i) {
        const float sp = sp_[i], sx = sx_[i];
        const float dis_r = __shfl(fx_[i], 16, 64);
        const float rdis = 1.0f / dis_r;
        const float sd = __shfl(sx, 16, 64);
        const float base = fmaf(sd, ub, sp);
#pragma unroll
        for (int b = 0; b < B; ++b) {
            float sx0 = __shfl(sx, b, 64);
            float sx1 = __shfl(sx, 8 + b, 64);
            float sc  = __shfl(fx_[i], 8 + b, 64) * rdis;   // score = x1[b][r]
            float mk  = __shfl(fx_[i], 17 + b, 64);         // pmask[b][r]
            float v = fmaf(sx0, u0, fmaf(sx1, u1, base));
            float z = fmaxf(fmaf(dis_r, v, bg), 0.f);
            atomicAdd(&lw[b * H + lane], z * sc);
            atomicAdd(&lp[b * H + lane], (z + __logf(1.f + __expf(-z))) * mk);
            if (r_[i] == tg[b]) tgt[b * H + lane] = z;
        }
        if (lane < 8) atomicAdd(&lnl[lane], fx_[i] * rdis); // x0[b][r]
    }
    __syncthreads();

    // block -> global: one atomic per element
    const int rep = blockIdx.x & (REPS - 1);
    atomicAdd(&wr_[rep * B * H + tid],       lw[tid]);
    atomicAdd(&wr_[rep * B * H + tid + 256], lw[tid + 256]);
    atomicAdd(&pr_[rep * B * H + tid],       lp[tid]);
    atomicAdd(&pr_[rep * B * H + tid + 256], lp[tid + 256]);
    if (tid < B) atomicAdd(&nlr[rep * B + tid], lnl[tid]);
}

// K4: reduce replicas, per-batch dots, sigmoid
__global__ __launch_bounds__(512) void k_final(const float* __restrict__ wr_,
                                               const float* __restrict__ pr_,
                                               const float* __restrict__ nlr,
                                               const float* __restrict__ tgt,
                                               const float* __restrict__ W_d,
                                               const float* __restrict__ b_d,
                                               const float* __restrict__ W_a,
                                               const float* __restrict__ b_a,
                                               const float* __restrict__ prereq_w,
                                               float* __restrict__ out) {
    int tid = threadIdx.x, b = tid >> 6, h = tid & 63;
    float ws = 0.f, ps = 0.f, nlv = 0.f;
#pragma unroll
    for (int rep = 0; rep < REPS; ++rep) {
        ws  += wr_[(rep * B + b) * H + h];
        ps  += pr_[(rep * B + b) * H + h];
        nlv += nlr[rep * B + b];
    }
    float nl = fmaxf(nlv, 1.0f);
    float ap = (ws / nl) * W_a[h];
    float dp = tgt[b * H + h] * W_d[h];
    float pp = ps;
    for (int off = 32; off; off >>= 1) {
        ap += __shfl_down(ap, off, 64);
        dp += __shfl_down(dp, off, 64);
        pp += __shfl_down(pp, off, 64);
    }
    if (h == 0) {
        float ability    = ap + b_a[0];
        float difficulty = dp + b_d[0];
        float preq       = fabsf(prereq_w[0]) * (pp * (1.0f / (float)H));
        float gap  = ability - difficulty + preq;
        float prob = 1.0f / (1.0f + __expf(-gap));
        out[b]     = prob;
        out[B + b] = gap;
    }
}

extern "C" void kernel_launch(void* const* d_in, const int* in_sizes, int n_in,
                              void* d_out, int out_size, void* d_ws, size_t ws_size,
                              hipStream_t stream) {
    const float* x        = (const float*)d_in[0];
    const int*   ei       = (const int*)d_in[1];
    const int*   target   = (const int*)d_in[2];
    const float* pmask    = (const float*)d_in[3];
    const float* ne       = (const float*)d_in[4];
    const float* W_sp     = (const float*)d_in[5];
    const float* b_sp     = (const float*)d_in[6];
    const float* W_g      = (const float*)d_in[7];
    const float* b_g      = (const float*)d_in[8];
    const float* W_d      = (const float*)d_in[9];
    const float* b_d      = (const float*)d_in[10];
    const float* W_a      = (const float*)d_in[11];
    const float* b_a      = (const float*)d_in[12];
    const float* prereq_w = (const float*)d_in[13];

    const int nE = in_sizes[1] / 2;

    char* ws = (char*)d_ws;
    unsigned*        cnt  = (unsigned*)(ws + OFF_CNT);
    float*           wr_  = (float*)(ws + OFF_WR);
    float*           pr_  = (float*)(ws + OFF_PR);
    float*           nlr  = (float*)(ws + OFF_NLR);
    unsigned short*  cols = (unsigned short*)(ws + OFF_COLS);
    float*           tgt  = (float*)(ws + OFF_TGT);
    float*           uvec = (float*)(ws + OFF_UV);
    unsigned*        rec  = (unsigned*)(ws + OFF_REC);

    // ws poisoned 0xAA once, never re-poisoned between replays -> zero every call
    k_zero<<<(unsigned)(ZERO_END / 16 + 255) / 256, 256, 0, stream>>>((float4*)ws);
    k_edges<<<(nE + 255) / 256, 256, 0, stream>>>(ei, nE, cnt, cols);
    k_prep<<<N / 8, 256, 0, stream>>>(ne, W_g, W_sp, b_sp, x, pmask, cnt, cols,
                                      rec, uvec);
    k_spmm<<<N / 16, 256, 0, stream>>>(rec, cnt, cols, uvec, b_g, target,
                                       wr_, pr_, nlr, tgt);
    k_final<<<1, 512, 0, stream>>>(wr_, pr_, nlr, tgt, W_d, b_d, W_a, b_a,
                                   prereq_w, (float*)d_out);
}

// Round 14
// 88.559 us; speedup vs baseline: 1.2803x; 1.2803x over previous
//
#include <hip/hip_runtime.h>
#include <hip/hip_fp16.h>
#include <math.h>

#define N 8192
#define H 64
#define B 8
#define MAXDEG 128
#define REPS 8

// ---- workspace layout (bytes) ----
// zeroed each call by k_zero:
#define OFF_CNT  0ULL            // 8192 u32 = 32768
#define OFF_WR   32768ULL        // REPS*8*64 f32 = 16384
#define OFF_PR   49152ULL        // 16384
#define OFF_NLR  65536ULL        // REPS*8 f32 = 256
#define ZERO_END 65792ULL        // /16 = 4112 float4
// not zeroed:
#define OFF_COLS 65792ULL        // 8192*128 u16 = 2,097,152
#define OFF_TGT  2162944ULL      // 512 f32 = 2048
#define OFF_UV   2164992ULL      // 3*64 f32 = 768
#define OFF_REC  2165760ULL      // 8193*64 u32 = 2,097,408 (256B rows; row N = zeros)
// end ~4.3 MB

// K0: zero cnt + replica accumulators (~64 KB) + the dummy rec row N
__global__ __launch_bounds__(256) void k_zero(float4* __restrict__ p,
                                              unsigned* __restrict__ recN) {
    unsigned i = blockIdx.x * 256u + threadIdx.x;
    if (i < (unsigned)(ZERO_END / 16))
        p[i] = make_float4(0.f, 0.f, 0.f, 0.f);
    if (blockIdx.x == 0 && threadIdx.x < 64) recN[threadIdx.x] = 0u;
}

// K1: append edges (1 edge/thread; dedup in K2)
__global__ __launch_bounds__(256) void k_edges(const int* __restrict__ ei, int nE,
                                               unsigned* __restrict__ cnt,
                                               unsigned short* __restrict__ cols) {
    int e = blockIdx.x * 256 + threadIdx.x;
    if (e >= nE) return;
    int r = ei[e];
    int c = ei[nE + e];
    unsigned k = atomicAdd(&cnt[r], 1u);
    if (k < MAXDEG) cols[r * MAXDEG + k] = (unsigned short)c;
}

// K2: per-wave {dedup -> pad-to-64 -> dis -> packed record}; uvec on blk0/wv0.
// rec[m][lane] u32 = f16(dis_m * (W_g@ne[m])_lane) << 16 | f16(aux_lane)
// aux: lane<8: dis*x0_b; 8..15: dis*x1_b; 16: dis; 17..24: pmask_b; else 0.
// cols[r][tot..64) = N (dummy row, zeros) so the gather loop is branchless.
__global__ __launch_bounds__(256) void k_prep(const float* __restrict__ ne,
                                              const float* __restrict__ W_g,
                                              const float* __restrict__ W_sp,
                                              const float* __restrict__ b_sp,
                                              const float* __restrict__ x,
                                              const float* __restrict__ pmask,
                                              unsigned* __restrict__ cnt,
                                              unsigned short* __restrict__ cols,
                                              unsigned* __restrict__ rec,
                                              float* __restrict__ uvec) {
    __shared__ float wgs[H * 65];                // padded W_g
    __shared__ unsigned short ls[4][MAXDEG];     // dedup staging
    const int tid = threadIdx.x, lane = tid & 63, wv = tid >> 6;
    const int bid = blockIdx.x;

    for (int e = tid; e < H * H; e += 256)
        wgs[(e >> 6) * 65 + (e & 63)] = W_g[e];
    __syncthreads();

    float wr[H];
#pragma unroll
    for (int k = 0; k < H; ++k) wr[k] = wgs[lane * 65 + k];

    if (bid == 0 && wv == 0) {   // uvec = {W_g@Wsp0, W_g@Wsp1, W_g@b_sp}
        float v0 = W_sp[lane * 2 + 0], v1 = W_sp[lane * 2 + 1], vb = b_sp[lane];
        float a0 = 0.f, a1 = 0.f, a2 = 0.f;
#pragma unroll
        for (int k = 0; k < H; ++k) {
            a0 = fmaf(wr[k], __shfl(v0, k, 64), a0);
            a1 = fmaf(wr[k], __shfl(v1, k, 64), a1);
            a2 = fmaf(wr[k], __shfl(vb, k, 64), a2);
        }
        uvec[lane] = a0; uvec[64 + lane] = a1; uvec[128 + lane] = a2;
    }

    for (int i = 0; i < 2; ++i) {
        const int r = (bid * 4 + wv) * 2 + i;
        // --- dedup row r ---
        const int kraw = min((int)cnt[r], MAXDEG);
        unsigned short* cl = &cols[r * MAXDEG];
        for (int t = lane; t < kraw; t += 64) ls[wv][t] = cl[t];
        int c0 = (lane < kraw) ? (int)ls[wv][lane] : -1;
        int dup0 = 0;
        for (int j = 0; j < lane && j < kraw; ++j)
            dup0 |= ((int)ls[wv][j] == c0);
        unsigned long long m0 = __ballot((lane < kraw) && !dup0);
        unsigned long long below = (1ULL << lane) - 1ULL;
        unsigned tot = __popcll(m0);
        if ((lane < kraw) && !dup0)
            cl[__popcll(m0 & below)] = (unsigned short)c0;
        if (kraw > 64) {                          // wave-uniform, rare
            const int i1 = lane + 64;
            int c1 = (i1 < kraw) ? (int)ls[wv][i1] : -2;
            int dup1 = 0;
            for (int j = 0; j < i1 && j < kraw; ++j)
                dup1 |= ((int)ls[wv][j] == c1);
            unsigned long long m1 = __ballot((i1 < kraw) && !dup1);
            if ((i1 < kraw) && !dup1)
                cl[tot + __popcll(m1 & below)] = (unsigned short)c1;
            tot += __popcll(m1);
        }
        if (lane == 0) cnt[r] = tot;
        // pad [tot, 64) with dummy index N (rec row N = zeros) -> branchless gather
        if (lane >= (int)tot && lane < 64) cl[lane] = (unsigned short)N;
        const float dis = rsqrtf((float)(tot + 1u));

        // --- aux for row r ---
        float xvx = 0.f, xvy = 0.f, pm = 0.f;
        if (lane < 8) {
            float2 t2 = ((const float2*)x)[lane * N + r];
            xvx = t2.x; xvy = t2.y;
        }
        if (lane >= 17 && lane < 25) pm = pmask[(lane - 17) * N + r];
        float yv = __shfl(xvy, lane & 7, 64);
        float aux = (lane < 8)   ? dis * xvx
                  : (lane < 16)  ? dis * yv
                  : (lane == 16) ? dis
                  : (lane < 25)  ? pm : 0.f;

        // --- P part: dis * (W_g @ ne[r])_lane ---
        const float4* ne4 = (const float4*)(ne + (size_t)r * H);
        float acc = 0.f;
#pragma unroll
        for (int kk = 0; kk < 16; ++kk) {
            float4 h4 = ne4[kk];
            acc = fmaf(wr[4 * kk + 0], h4.x, acc);
            acc = fmaf(wr[4 * kk + 1], h4.y, acc);
            acc = fmaf(wr[4 * kk + 2], h4.z, acc);
            acc = fmaf(wr[4 * kk + 3], h4.w, acc);
        }
        unsigned w = ((unsigned)__half_as_ushort(__float2half(dis * acc)) << 16)
                   |  (unsigned)__half_as_ushort(__float2half(aux));
        rec[(size_t)r * 64 + lane] = w;
    }
}

__device__ __forceinline__ void acc_u32(unsigned u, float& p, float& a) {
    float2 f = __half22float2(*(const __half2*)&u);   // .y = P (hi), .x = aux (lo)
    p += f.y; a += f.x;
}

// K3: gather phase — branchless chunked load-all-then-consume.
// 1 row/wave, 8192 waves (512 blocks x 1024 thr, 2 blocks/CU). Col list padded
// to 64 with dummy row N (zeros, hot in L1). Each chunk: 16 shfl-broadcast
// indices, then 16 UNCONDITIONAL independent loads issued back-to-back
// (static arrays + full unroll -> registers, guaranteed 16-deep vmem pipeline),
// then consume. Wave-uniform chunk skip for kc<48. LDS block reduction as R11.
__global__ __launch_bounds__(1024, 2) void k_spmm(const unsigned* __restrict__ rec,
                                                  const unsigned* __restrict__ cnt,
                                                  const unsigned short* __restrict__ cols,
                                                  const float* __restrict__ uvec,
                                                  const float* __restrict__ b_g,
                                                  const int* __restrict__ target,
                                                  float* __restrict__ wr_,
                                                  float* __restrict__ pr_,
                                                  float* __restrict__ nlr,
                                                  float* __restrict__ tgt) {
    __shared__ float lw[B * H];
    __shared__ float lp[B * H];
    __shared__ float lnl[B];
    const int tid = threadIdx.x;
    const int lane = tid & 63, wv = tid >> 6;
    const int r = blockIdx.x * 16 + wv;

    if (tid < B * H) { lw[tid] = 0.f; lp[tid] = 0.f; }
    if (tid < B) lnl[tid] = 0.f;
    __syncthreads();

    const float u0 = uvec[lane], u1 = uvec[64 + lane], ub = uvec[128 + lane];
    const float bg = b_g[lane];
    int tg[B];
#pragma unroll
    for (int b = 0; b < B; ++b) tg[b] = target[b];

    const unsigned vown = rec[(size_t)r * 64 + lane];
    float2 fown = __half22float2(*(const __half2*)&vown);  // .y = P, .x = aux

    const int kc = min((int)cnt[r], MAXDEG);
    const unsigned short* cl = &cols[r * MAXDEG];
    const int creg = (int)cl[lane];               // one coalesced load of 64 padded cols

    float sp = fown.y, sx = fown.x;               // eye term
#pragma unroll
    for (int ch = 0; ch < 4; ++ch) {
        if (ch * 16 < kc) {                       // wave-uniform skip
            int c[16];
#pragma unroll
            for (int j = 0; j < 16; ++j) c[j] = __shfl(creg, ch * 16 + j, 64);
            unsigned v[16];
#pragma unroll
            for (int j = 0; j < 16; ++j) v[j] = rec[(size_t)c[j] * 64 + lane];
#pragma unroll
            for (int j = 0; j < 16; ++j) acc_u32(v[j], sp, sx);
        }
    }
    for (int kk = 64; kk < kc; ++kk) {            // rare tail (deg > 64)
        int c = (int)cl[kk];
        unsigned v = rec[(size_t)c * 64 + lane];
        float2 f = __half22float2(*(const __half2*)&v);
        sp += f.y; sx += f.x;
    }

    // ---- epilogue: reconstruct z per batch, accumulate into LDS ----
    const float dis_r = __shfl(fown.x, 16, 64);
    const float rdis = 1.0f / dis_r;
    const float sd = __shfl(sx, 16, 64);
    const float base = fmaf(sd, ub, sp);
#pragma unroll
    for (int b = 0; b < B; ++b) {
        float sx0 = __shfl(sx, b, 64);
        float sx1 = __shfl(sx, 8 + b, 64);
        float sc  = __shfl(fown.x, 8 + b, 64) * rdis;      // score = x1[b][r]
        float mk  = __shfl(fown.x, 17 + b, 64);            // pmask[b][r]
        float v = fmaf(sx0, u0, fmaf(sx1, u1, base));
        float z = fmaxf(fmaf(dis_r, v, bg), 0.f);
        atomicAdd(&lw[b * H + lane], z * sc);
        atomicAdd(&lp[b * H + lane], (z + __logf(1.f + __expf(-z))) * mk);
        if (r == tg[b]) tgt[b * H + lane] = z;
    }
    if (lane < 8) atomicAdd(&lnl[lane], fown.x * rdis);    // x0[b][r]
    __syncthreads();

    // block -> global: one atomic per element
    const int rep = blockIdx.x & (REPS - 1);
    if (tid < B * H)           atomicAdd(&wr_[rep * B * H + tid], lw[tid]);
    else if (tid < 2 * B * H)  atomicAdd(&pr_[rep * B * H + tid - B * H], lp[tid - B * H]);
    if (tid < B)               atomicAdd(&nlr[rep * B + tid], lnl[tid]);
}

// K4: reduce replicas, per-batch dots, sigmoid
__global__ __launch_bounds__(512) void k_final(const float* __restrict__ wr_,
                                               const float* __restrict__ pr_,
                                               const float* __restrict__ nlr,
                                               const float* __restrict__ tgt,
                                               const float* __restrict__ W_d,
                                               const float* __restrict__ b_d,
                                               const float* __restrict__ W_a,
                                               const float* __restrict__ b_a,
                                               const float* __restrict__ prereq_w,
                                               float* __restrict__ out) {
    int tid = threadIdx.x, b = tid >> 6, h = tid & 63;
    float ws = 0.f, ps = 0.f, nlv = 0.f;
#pragma unroll
    for (int rep = 0; rep < REPS; ++rep) {
        ws  += wr_[(rep * B + b) * H + h];
        ps  += pr_[(rep * B + b) * H + h];
        nlv += nlr[rep * B + b];
    }
    float nl = fmaxf(nlv, 1.0f);
    float ap = (ws / nl) * W_a[h];
    float dp = tgt[b * H + h] * W_d[h];
    float pp = ps;
    for (int off = 32; off; off >>= 1) {
        ap += __shfl_down(ap, off, 64);
        dp += __shfl_down(dp, off, 64);
        pp += __shfl_down(pp, off, 64);
    }
    if (h == 0) {
        float ability    = ap + b_a[0];
        float difficulty = dp + b_d[0];
        float preq       = fabsf(prereq_w[0]) * (pp * (1.0f / (float)H));
        float gap  = ability - difficulty + preq;
        float prob = 1.0f / (1.0f + __expf(-gap));
        out[b]     = prob;
        out[B + b] = gap;
    }
}

extern "C" void kernel_launch(void* const* d_in, const int* in_sizes, int n_in,
                              void* d_out, int out_size, void* d_ws, size_t ws_size,
                              hipStream_t stream) {
    const float* x        = (const float*)d_in[0];
    const int*   ei       = (const int*)d_in[1];
    const int*   target   = (const int*)d_in[2];
    const float* pmask    = (const float*)d_in[3];
    const float* ne       = (const float*)d_in[4];
    const float* W_sp     = (const float*)d_in[5];
    const float* b_sp     = (const float*)d_in[6];
    const float* W_g      = (const float*)d_in[7];
    const float* b_g      = (const float*)d_in[8];
    const float* W_d      = (const float*)d_in[9];
    const float* b_d      = (const float*)d_in[10];
    const float* W_a      = (const float*)d_in[11];
    const float* b_a      = (const float*)d_in[12];
    const float* prereq_w = (const float*)d_in[13];

    const int nE = in_sizes[1] / 2;

    char* ws = (char*)d_ws;
    unsigned*        cnt  = (unsigned*)(ws + OFF_CNT);
    float*           wr_  = (float*)(ws + OFF_WR);
    float*           pr_  = (float*)(ws + OFF_PR);
    float*           nlr  = (float*)(ws + OFF_NLR);
    unsigned short*  cols = (unsigned short*)(ws + OFF_COLS);
    float*           tgt  = (float*)(ws + OFF_TGT);
    float*           uvec = (float*)(ws + OFF_UV);
    unsigned*        rec  = (unsigned*)(ws + OFF_REC);

    // ws poisoned 0xAA once, never re-poisoned between replays -> zero every call
    k_zero<<<(unsigned)(ZERO_END / 16 + 255) / 256, 256, 0, stream>>>(
        (float4*)ws, rec + (size_t)N * 64);
    k_edges<<<(nE + 255) / 256, 256, 0, stream>>>(ei, nE, cnt, cols);
    k_prep<<<N / 8, 256, 0, stream>>>(ne, W_g, W_sp, b_sp, x, pmask, cnt, cols,
                                      rec, uvec);
    k_spmm<<<N / 16, 1024, 0, stream>>>(rec, cnt, cols, uvec, b_g, target,
                                        wr_, pr_, nlr, tgt);
    k_final<<<1, 512, 0, stream>>>(wr_, pr_, nlr, tgt, W_d, b_d, W_a, b_a,
                                   prereq_w, (float*)d_out);
}